// Round 4
// baseline (10633.943 us; speedup 1.0000x reference)
//
#include <hip/hip_runtime.h>
#include <math.h>

#define SEQ 512
#define BAT 32
#define HID 512
#define NG  3072   // 4H gates + H (r) + H (xl)
#define CH  32     // time chunk
#define NB  32     // scan blocks (16 units each)
#define UPB 16     // units per block
#define LSTR 520   // h_lds row stride in bf16 elems (65 x 16B granules, odd -> spread)
#define DSTR 81    // Dst row stride (floats, odd -> conflict-free pointwise reads)

typedef __attribute__((ext_vector_type(8))) short bfrag;
typedef __attribute__((ext_vector_type(4))) float f32x4;
typedef unsigned long long u64;

__device__ __forceinline__ float sigf(float x) { return 1.f / (1.f + expf(-x)); }

__device__ __forceinline__ unsigned short f2bf(float x) {
    unsigned u = __float_as_uint(x);
    return (unsigned short)((u + 0x7fffu + ((u >> 16) & 1u)) >> 16);
}

// ---------------------------------------------------------------------------
// Input projection GEMM (fp32, NT) — unchanged (verified rounds 0-3).
#define BM 64
#define BN 64
#define BK 32
__global__ __launch_bounds__(256) void proj_gemm(
    const float* __restrict__ xin, int t0, int rev,
    const float* __restrict__ Wih, const float* __restrict__ Wgi,
    const float* __restrict__ Wli,
    const float* __restrict__ bih, const float* __restrict__ bhh,
    const float* __restrict__ bgi, const float* __restrict__ bgs,
    float* __restrict__ P)
{
    __shared__ float As[BK][BM + 4];
    __shared__ float Bs[BK][BN + 4];

    const int tid = threadIdx.x;
    const int bm = blockIdx.x;
    const int bn = blockIdx.y;
    const int tx = tid & 15;
    const int ty = tid >> 4;

    float acc[4][4];
#pragma unroll
    for (int i = 0; i < 4; i++)
#pragma unroll
        for (int j = 0; j < 4; j++) acc[i][j] = 0.f;

    for (int k0 = 0; k0 < HID; k0 += BK) {
#pragma unroll
        for (int i = 0; i < 2; i++) {
            int f = tid + i * 256;
            int m = f >> 3, kq = f & 7;
            int gm = bm * 64 + m;
            int t = t0 + (gm >> 5), b = gm & 31;
            int pt = rev ? (SEQ - 1 - t) : t;
            const float* ap = xin + ((size_t)pt * BAT + b) * HID + k0 + kq * 4;
            float4 a4 = *(const float4*)ap;
            As[kq * 4 + 0][m] = a4.x;
            As[kq * 4 + 1][m] = a4.y;
            As[kq * 4 + 2][m] = a4.z;
            As[kq * 4 + 3][m] = a4.w;
        }
#pragma unroll
        for (int i = 0; i < 2; i++) {
            int f = tid + i * 256;
            int n = f >> 3, kq = f & 7;
            int gn = bn * 64 + n;
            const float* wrow = (gn < 2048) ? (Wih + (size_t)gn * HID)
                              : (gn < 2560) ? (Wgi + (size_t)(gn - 2048) * HID)
                                            : (Wli + (size_t)(gn - 2560) * HID);
            float4 b4 = *(const float4*)(wrow + k0 + kq * 4);
            Bs[kq * 4 + 0][n] = b4.x;
            Bs[kq * 4 + 1][n] = b4.y;
            Bs[kq * 4 + 2][n] = b4.z;
            Bs[kq * 4 + 3][n] = b4.w;
        }
        __syncthreads();
#pragma unroll
        for (int k = 0; k < BK; k++) {
            float4 a4 = *(const float4*)&As[k][ty * 4];
            float4 b4 = *(const float4*)&Bs[k][tx * 4];
            float a[4] = {a4.x, a4.y, a4.z, a4.w};
            float b[4] = {b4.x, b4.y, b4.z, b4.w};
#pragma unroll
            for (int i = 0; i < 4; i++)
#pragma unroll
                for (int j = 0; j < 4; j++) acc[i][j] += a[i] * b[j];
        }
        __syncthreads();
    }

    int gnb = bn * 64 + tx * 4;
    float bias[4];
#pragma unroll
    for (int j = 0; j < 4; j++) {
        int gn = gnb + j;
        bias[j] = (gn < 2048) ? (bih[gn] + bhh[gn])
                : (gn < 2560) ? (bgi[gn - 2048] + bgs[gn - 2048])
                              : 0.f;
    }
#pragma unroll
    for (int i = 0; i < 4; i++) {
        int m = bm * 64 + ty * 4 + i;
        float4 o;
        o.x = acc[i][0] + bias[0];
        o.y = acc[i][1] + bias[1];
        o.z = acc[i][2] + bias[2];
        o.w = acc[i][3] + bias[3];
        *(float4*)(P + (size_t)m * NG + gnb) = o;
    }
}

// ---------------------------------------------------------------------------
// Persistent scan. 32 blocks x 256 threads. Recurrent weights live in
// per-wave MFMA B-fragments (registers) for the whole chunk. h exchanged
// via tagged u64 words: {bf16 lo unit, bf16 hi unit, u32 step tag} —
// single-word atomicity makes data+tag coherent, so no fences, no flags.
// Two-parity buffer: publishing h_{t+1} requires having consumed everyone's
// h_t, so the slot being overwritten (h_{t-1}) is no longer read by anyone.
__global__ __launch_bounds__(256, 1) void scan_chunk(
    const float* __restrict__ P,      // [CH][32][3072]
    const float* __restrict__ Whh,    // [2048][512]
    const float* __restrict__ Wgs,    // [512][512]
    u64* __restrict__ Htag,           // [2][32][256] tagged h words
    float* __restrict__ Hf32,         // [32][512] per-thread h (fp32) persist
    float* __restrict__ Cbuf,         // [32][512] c persist
    const float* __restrict__ mask,   // [512][32]
    const float* __restrict__ dm,     // [32][512]
    float* __restrict__ Y,            // layer0 out [512][32][512]
    float* __restrict__ out,          // final out [32][512][512]
    int l, int c,
    const int* __restrict__ trainPtr)
{
    __shared__ unsigned short h_lds[BAT * LSTR]; // 33,280 B
    __shared__ float Dst[BAT * DSTR];            // 10,368 B
    __shared__ float hout[BAT * UPB];            //  2,048 B

    const int tid = threadIdx.x;
    const int u0 = blockIdx.x * UPB;
    const int b = tid & 31;
    const int ul = tid >> 5;          // 0..7
    const int lane = tid & 63;
    const int wv = tid >> 6;
    const int rev = (l == 1);
    const int row15 = lane & 15;
    const int koff = (lane >> 4) * 8;

    // ---- wave -> tile map: wave owns M-tile mtw and N-tiles {ntA0, ntA0+1}
    //      plus N-tile 4 (the r-gate) on even waves.
    const int mtw  = wv >> 1;         // 0,0,1,1
    const int ntA0 = (wv & 1) * 2;    // 0,2,0,2
    const int hasB = !(wv & 1);

    // ---- load B fragments into registers (once per chunk, bf16-converted)
    // B-frag lane layout: row n = nt*16 + row15, k = koff + ks*32 + 0..7
    bfrag wA0[16], wA1[16], wB[16];
    {
        const float* r0 = Whh + ((size_t)(ntA0 * 512 + u0 + row15)) * 512;
        const float* r1 = Whh + ((size_t)((ntA0 + 1) * 512 + u0 + row15)) * 512;
        const float* r2 = Wgs + (size_t)(u0 + row15) * 512;
#pragma unroll
        for (int ks = 0; ks < 16; ks++) {
            int k = koff + ks * 32;
            float4 x0, x1;
            bfrag f;
            x0 = *(const float4*)(r0 + k); x1 = *(const float4*)(r0 + k + 4);
            f[0] = (short)f2bf(x0.x); f[1] = (short)f2bf(x0.y);
            f[2] = (short)f2bf(x0.z); f[3] = (short)f2bf(x0.w);
            f[4] = (short)f2bf(x1.x); f[5] = (short)f2bf(x1.y);
            f[6] = (short)f2bf(x1.z); f[7] = (short)f2bf(x1.w);
            wA0[ks] = f;
            x0 = *(const float4*)(r1 + k); x1 = *(const float4*)(r1 + k + 4);
            f[0] = (short)f2bf(x0.x); f[1] = (short)f2bf(x0.y);
            f[2] = (short)f2bf(x0.z); f[3] = (short)f2bf(x0.w);
            f[4] = (short)f2bf(x1.x); f[5] = (short)f2bf(x1.y);
            f[6] = (short)f2bf(x1.z); f[7] = (short)f2bf(x1.w);
            wA1[ks] = f;
            if (hasB) {
                x0 = *(const float4*)(r2 + k); x1 = *(const float4*)(r2 + k + 4);
                f[0] = (short)f2bf(x0.x); f[1] = (short)f2bf(x0.y);
                f[2] = (short)f2bf(x0.z); f[3] = (short)f2bf(x0.w);
                f[4] = (short)f2bf(x1.x); f[5] = (short)f2bf(x1.y);
                f[6] = (short)f2bf(x1.z); f[7] = (short)f2bf(x1.w);
            }
            wB[ks] = f;
        }
    }

    // ---- persistent per-thread state: (batch b, units u0+ul, u0+ul+8)
    float h0 = Hf32[b * HID + u0 + ul];
    float h1 = Hf32[b * HID + u0 + ul + 8];
    float c0 = Cbuf[b * HID + u0 + ul];
    float c1 = Cbuf[b * HID + u0 + ul + 8];
    const int train = *trainPtr;
    const float dm0 = train ? dm[b * HID + u0 + ul] : 1.0f;
    const float dm1 = train ? dm[b * HID + u0 + ul + 8] : 1.0f;

    for (int s = 0; s < CH; s++) {
        const int t = c * CH + s;
        const int par = t & 1;
        const int tPhys = rev ? (SEQ - 1 - t) : t;

        // --- prefetch P / mask (independent of h)
        const float* Pb = P + ((size_t)s * BAT + b) * NG;
        float pi0 = Pb[u0 + ul],        pi1 = Pb[u0 + ul + 8];
        float pf0 = Pb[512 + u0 + ul],  pf1 = Pb[512 + u0 + ul + 8];
        float pg0 = Pb[1024 + u0 + ul], pg1 = Pb[1024 + u0 + ul + 8];
        float po0 = Pb[1536 + u0 + ul], po1 = Pb[1536 + u0 + ul + 8];
        float pr0 = Pb[2048 + u0 + ul], pr1 = Pb[2048 + u0 + ul + 8];
        float xl0 = Pb[2560 + u0 + ul], xl1 = Pb[2560 + u0 + ul + 8];
        float mk  = mask[(size_t)tPhys * BAT + b];

        // --- gather h_t: poll tagged words (expect tag == t), stage to LDS
        {
            const u64* src = Htag + (size_t)par * 8192 + b * 256 + ul * 32;
            u64 v[32];
#pragma unroll
            for (int j = 0; j < 32; j++)
                v[j] = __hip_atomic_load(src + j, __ATOMIC_RELAXED,
                                         __HIP_MEMORY_SCOPE_AGENT);
            const unsigned ex = (unsigned)t;
            while (true) {
                unsigned bad = 0;
#pragma unroll
                for (int j = 0; j < 32; j++) bad |= ((unsigned)(v[j] >> 32)) ^ ex;
                if (!bad) break;
#pragma unroll
                for (int j = 0; j < 32; j++)
                    if (((unsigned)(v[j] >> 32)) != ex)
                        v[j] = __hip_atomic_load(src + j, __ATOMIC_RELAXED,
                                                 __HIP_MEMORY_SCOPE_AGENT);
            }
            // units covered: ul*64 + 2j, 2j+1  -> pack 4 words per b128 store
#pragma unroll
            for (int m = 0; m < 8; m++) {
                uint4 wq;
                wq.x = (unsigned)v[4 * m];
                wq.y = (unsigned)v[4 * m + 1];
                wq.z = (unsigned)v[4 * m + 2];
                wq.w = (unsigned)v[4 * m + 3];
                *(uint4*)&h_lds[b * LSTR + ul * 64 + m * 8] = wq;
            }
        }
        __syncthreads();

        // --- MFMA: D[m=batch][n=unit] = sum_k h[m][k] * w[n][k]
        {
            f32x4 ac0 = {0.f, 0.f, 0.f, 0.f};
            f32x4 ac1 = {0.f, 0.f, 0.f, 0.f};
            f32x4 acB = {0.f, 0.f, 0.f, 0.f};
            const unsigned short* ha = &h_lds[(mtw * 16 + row15) * LSTR + koff];
#pragma unroll
            for (int ks = 0; ks < 16; ks++) {
                bfrag a = *(const bfrag*)(ha + ks * 32);
                ac0 = __builtin_amdgcn_mfma_f32_16x16x32_bf16(a, wA0[ks], ac0, 0, 0, 0);
                ac1 = __builtin_amdgcn_mfma_f32_16x16x32_bf16(a, wA1[ks], ac1, 0, 0, 0);
                if (hasB)
                    acB = __builtin_amdgcn_mfma_f32_16x16x32_bf16(a, wB[ks], acB, 0, 0, 0);
            }
            int mr  = mtw * 16 + (lane >> 4) * 4;
            int cl0 = ntA0 * 16 + row15;
#pragma unroll
            for (int r = 0; r < 4; r++) {
                Dst[(mr + r) * DSTR + cl0]      = ac0[r];
                Dst[(mr + r) * DSTR + cl0 + 16] = ac1[r];
            }
            if (hasB) {
                int clB = 64 + row15;
#pragma unroll
                for (int r = 0; r < 4; r++) Dst[(mr + r) * DSTR + clB] = acB[r];
            }
        }
        __syncthreads();

        // --- pointwise (fp32): gate g at Dst cols g*16 + unit_local
        float hn0, hn1;
        {
            float gi = sigf(pi0 + Dst[b * DSTR + 0  + ul]);
            float gf = sigf(pf0 + Dst[b * DSTR + 16 + ul]);
            float gg = tanhf(pg0 + Dst[b * DSTR + 32 + ul]);
            float go = sigf(po0 + Dst[b * DSTR + 48 + ul]);
            float gr = sigf(pr0 + Dst[b * DSTR + 64 + ul]);
            float ct = gf * c0 + gi * gg;
            float hr_ = go * tanhf(ct);
            float h2 = (gr * hr_ + (1.f - gr) * xl0) * dm0;
            hn0 = mk * h2 + (1.f - mk) * h0;
            c0  = mk * ct + (1.f - mk) * c0;
            h0  = hn0;
        }
        {
            float gi = sigf(pi1 + Dst[b * DSTR + 8  + ul]);
            float gf = sigf(pf1 + Dst[b * DSTR + 24 + ul]);
            float gg = tanhf(pg1 + Dst[b * DSTR + 40 + ul]);
            float go = sigf(po1 + Dst[b * DSTR + 56 + ul]);
            float gr = sigf(pr1 + Dst[b * DSTR + 72 + ul]);
            float ct = gf * c1 + gi * gg;
            float hr_ = go * tanhf(ct);
            float h2 = (gr * hr_ + (1.f - gr) * xl1) * dm1;
            hn1 = mk * h2 + (1.f - mk) * h1;
            c1  = mk * ct + (1.f - mk) * c1;
            h1  = hn1;
        }
        hout[b * UPB + ul]     = hn0;
        hout[b * UPB + ul + 8] = hn1;

        if (l == 0) {
            Y[(size_t)t * BAT * HID + b * HID + u0 + ul]     = hn0;
            Y[(size_t)t * BAT * HID + b * HID + u0 + ul + 8] = hn1;
        } else {
            out[(size_t)b * SEQ * HID + (size_t)(SEQ - 1 - t) * HID + u0 + ul]     = hn0;
            out[(size_t)b * SEQ * HID + (size_t)(SEQ - 1 - t) * HID + u0 + ul + 8] = hn1;
        }
        __syncthreads();   // hout ready for publishers

        // --- publish h_{t+1}: tagged words, no fence, no flag
        {
            unsigned short lo = f2bf(hout[b * UPB + 2 * ul]);
            unsigned short hi = f2bf(hout[b * UPB + 2 * ul + 1]);
            u64 pv = (u64)lo | ((u64)hi << 16) | ((u64)(unsigned)(t + 1) << 32);
            __hip_atomic_store(&Htag[(size_t)(par ^ 1) * 8192 + b * 256 + (u0 >> 1) + ul],
                               pv, __ATOMIC_RELAXED, __HIP_MEMORY_SCOPE_AGENT);
        }
    }

    // persist state for next chunk
    Hf32[b * HID + u0 + ul]     = h0;
    Hf32[b * HID + u0 + ul + 8] = h1;
    Cbuf[b * HID + u0 + ul]     = c0;
    Cbuf[b * HID + u0 + ul + 8] = c1;
}

// ---------------------------------------------------------------------------
extern "C" void kernel_launch(void* const* d_in, const int* in_sizes, int n_in,
                              void* d_out, int out_size, void* d_ws, size_t ws_size,
                              hipStream_t stream) {
    const float* x        = (const float*)d_in[0];
    const float* mask     = (const float*)d_in[1];
    const float* W_ih     = (const float*)d_in[2];
    const float* b_ih     = (const float*)d_in[3];
    const float* W_hh     = (const float*)d_in[4];
    const float* b_hh     = (const float*)d_in[5];
    const float* Wg_in    = (const float*)d_in[6];
    const float* bg_in    = (const float*)d_in[7];
    const float* Wg_state = (const float*)d_in[8];
    const float* bg_state = (const float*)d_in[9];
    const float* Wl_in    = (const float*)d_in[10];
    const float* drop     = (const float*)d_in[11];
    const int*   train    = (const int*)d_in[12];
    float* out = (float*)d_out;

    // ws layout:
    //   P     : CH*32*3072 fp32   = 12.58 MB
    //   Y     : 512*32*512 fp32   = 33.55 MB
    //   Htag  : 2*32*256 u64      = 128 KB
    //   Hf32  : 32*512 fp32       = 64 KB
    //   Cbuf  : 32*512 fp32       = 64 KB
    float* P    = (float*)d_ws;
    float* Y    = P + (size_t)CH * BAT * NG;
    u64*   Htag = (u64*)(Y + (size_t)SEQ * BAT * HID);
    float* Hf32 = (float*)(Htag + 2 * BAT * 256);
    float* Cbuf = Hf32 + BAT * HID;

    for (int l = 0; l < 2; l++) {
        const int rev = l;
        const float* Wih = W_ih + (size_t)l * 4 * HID * HID;
        const float* Whh = W_hh + (size_t)l * 4 * HID * HID;
        const float* Wgi = Wg_in + (size_t)l * HID * HID;
        const float* Wli = Wl_in + (size_t)l * HID * HID;
        const float* bih = b_ih + (size_t)l * 4 * HID;
        const float* bhh = b_hh + (size_t)l * 4 * HID;
        const float* bgi = bg_in + (size_t)l * HID;
        const float* dm  = drop + (size_t)l * BAT * HID;
        const float* xin = l ? Y : x;

        // zero Htag (tags -> 0 == expected tag at t=0, data -> h_0 = 0),
        // plus Hf32 + Cbuf (contiguous 256 KB)
        hipMemsetAsync(Htag, 0,
                       (size_t)2 * BAT * 256 * 8 + (size_t)2 * BAT * HID * 4,
                       stream);

        for (int c = 0; c < SEQ / CH; c++) {
            proj_gemm<<<dim3((CH * BAT) / BM, NG / BN), 256, 0, stream>>>(
                xin, c * CH, rev, Wih, Wgi, Wli, bih, bhh, bgi, bg_state, P);
            scan_chunk<<<NB, 256, 0, stream>>>(
                P, Whh, Wg_state, Htag, Hf32, Cbuf, mask, dm, Y, out,
                l, c, train);
        }
    }
}

// Round 5
// 7544.785 us; speedup vs baseline: 1.4094x; 1.4094x over previous
//
#include <hip/hip_runtime.h>
#include <math.h>

#define SEQ 512
#define BAT 32
#define HID 512
#define NG  3072   // 4H gates + H (r) + H (xl)
#define CH  32     // time chunk
#define NB  32     // scan blocks (16 units each)
#define UPB 16     // units per block
#define LSTR 520   // h_lds row stride (bf16 elems, 16B-aligned rows, 2-way max on b128)
#define DSTR 81    // Dst row stride (floats, odd -> conflict-free)

typedef __attribute__((ext_vector_type(8))) short bfrag;
typedef __attribute__((ext_vector_type(4))) float f32x4;
typedef unsigned long long u64;

__device__ __forceinline__ float sigf(float x) { return 1.f / (1.f + expf(-x)); }

__device__ __forceinline__ unsigned short f2bf(float x) {
    unsigned u = __float_as_uint(x);
    return (unsigned short)((u + 0x7fffu + ((u >> 16) & 1u)) >> 16);
}

// ---------------------------------------------------------------------------
// Input projection GEMM (fp32, NT) — unchanged (verified rounds 0-4).
#define BM 64
#define BN 64
#define BK 32
__global__ __launch_bounds__(256) void proj_gemm(
    const float* __restrict__ xin, int t0, int rev,
    const float* __restrict__ Wih, const float* __restrict__ Wgi,
    const float* __restrict__ Wli,
    const float* __restrict__ bih, const float* __restrict__ bhh,
    const float* __restrict__ bgi, const float* __restrict__ bgs,
    float* __restrict__ P)
{
    __shared__ float As[BK][BM + 4];
    __shared__ float Bs[BK][BN + 4];

    const int tid = threadIdx.x;
    const int bm = blockIdx.x;
    const int bn = blockIdx.y;
    const int tx = tid & 15;
    const int ty = tid >> 4;

    float acc[4][4];
#pragma unroll
    for (int i = 0; i < 4; i++)
#pragma unroll
        for (int j = 0; j < 4; j++) acc[i][j] = 0.f;

    for (int k0 = 0; k0 < HID; k0 += BK) {
#pragma unroll
        for (int i = 0; i < 2; i++) {
            int f = tid + i * 256;
            int m = f >> 3, kq = f & 7;
            int gm = bm * 64 + m;
            int t = t0 + (gm >> 5), b = gm & 31;
            int pt = rev ? (SEQ - 1 - t) : t;
            const float* ap = xin + ((size_t)pt * BAT + b) * HID + k0 + kq * 4;
            float4 a4 = *(const float4*)ap;
            As[kq * 4 + 0][m] = a4.x;
            As[kq * 4 + 1][m] = a4.y;
            As[kq * 4 + 2][m] = a4.z;
            As[kq * 4 + 3][m] = a4.w;
        }
#pragma unroll
        for (int i = 0; i < 2; i++) {
            int f = tid + i * 256;
            int n = f >> 3, kq = f & 7;
            int gn = bn * 64 + n;
            const float* wrow = (gn < 2048) ? (Wih + (size_t)gn * HID)
                              : (gn < 2560) ? (Wgi + (size_t)(gn - 2048) * HID)
                                            : (Wli + (size_t)(gn - 2560) * HID);
            float4 b4 = *(const float4*)(wrow + k0 + kq * 4);
            Bs[kq * 4 + 0][n] = b4.x;
            Bs[kq * 4 + 1][n] = b4.y;
            Bs[kq * 4 + 2][n] = b4.z;
            Bs[kq * 4 + 3][n] = b4.w;
        }
        __syncthreads();
#pragma unroll
        for (int k = 0; k < BK; k++) {
            float4 a4 = *(const float4*)&As[k][ty * 4];
            float4 b4 = *(const float4*)&Bs[k][tx * 4];
            float a[4] = {a4.x, a4.y, a4.z, a4.w};
            float b[4] = {b4.x, b4.y, b4.z, b4.w};
#pragma unroll
            for (int i = 0; i < 4; i++)
#pragma unroll
                for (int j = 0; j < 4; j++) acc[i][j] += a[i] * b[j];
        }
        __syncthreads();
    }

    int gnb = bn * 64 + tx * 4;
    float bias[4];
#pragma unroll
    for (int j = 0; j < 4; j++) {
        int gn = gnb + j;
        bias[j] = (gn < 2048) ? (bih[gn] + bhh[gn])
                : (gn < 2560) ? (bgi[gn - 2048] + bgs[gn - 2048])
                              : 0.f;
    }
#pragma unroll
    for (int i = 0; i < 4; i++) {
        int m = bm * 64 + ty * 4 + i;
        float4 o;
        o.x = acc[i][0] + bias[0];
        o.y = acc[i][1] + bias[1];
        o.z = acc[i][2] + bias[2];
        o.w = acc[i][3] + bias[3];
        *(float4*)(P + (size_t)m * NG + gnb) = o;
    }
}

// ---------------------------------------------------------------------------
// Persistent scan. 32 blocks x 512 threads (8 waves). Recurrent weights in
// per-wave register B-fragments. h exchanged via tagged u64 words
// {bf16 unit 2p, bf16 unit 2p+1, u32 step tag} in unit-pair-major layout
// Htag[par][upair*32 + b] -> COALESCED publish (lanes 0-31 consecutive) and
// COALESCED gather (j*512+tid). Single-word atomicity => no fences/flags.
// Two-parity buffer: publishing h_{t+1} implies h_t fully consumed, so the
// overwritten h_{t-1} slots are dead (proof as rounds 3/4).
__global__ __launch_bounds__(512, 1) void scan_chunk(
    const float* __restrict__ P,      // [CH][32][3072]
    const float* __restrict__ Whh,    // [2048][512]
    const float* __restrict__ Wgs,    // [512][512]
    u64* __restrict__ Htag,           // [2][8192] tagged words
    float* __restrict__ Hf32,         // [32][512] persist
    float* __restrict__ Cbuf,         // [32][512] persist
    const float* __restrict__ mask,   // [512][32]
    const float* __restrict__ dm,     // [32][512]
    float* __restrict__ Y,            // layer0 out [512][32][512]
    float* __restrict__ out,          // final out [32][512][512]
    int l, int c,
    const int* __restrict__ trainPtr)
{
    __shared__ unsigned short h_lds[BAT * LSTR]; // 33,280 B
    __shared__ float Dst[BAT * DSTR];            // 10,368 B

    const int tid = threadIdx.x;      // 0..511
    const int u0 = blockIdx.x * UPB;
    const int b = tid & 31;
    const int ul = tid >> 5;          // 0..15  (unit local)
    const int lane = tid & 63;
    const int wv = tid >> 6;          // 0..7
    const int rev = (l == 1);
    const int row15 = lane & 15;
    const int koff = (lane >> 4) * 8;

    // ---- wave -> MFMA tile map: tile idx = mt*5 + nt (mt: batch 16-row tile,
    //      nt: gate). Wave wv owns idx wv; waves 0,1 also own idx 8,9.
    const int mtA = wv / 5, ntA = wv % 5;
    const int has2 = (wv < 2);
    const int mtB = 1, ntB = 3 + wv;  // idx 8,9 (only used when has2)

    // ---- load B fragments (once per chunk, bf16): row n = nt*16+row15
    bfrag wA[16], wB[16];
    {
        const float* rA = (ntA < 4) ? (Whh + ((size_t)(ntA * 512 + u0 + row15)) * 512)
                                    : (Wgs + (size_t)(u0 + row15) * 512);
#pragma unroll
        for (int ks = 0; ks < 16; ks++) {
            int k = koff + ks * 32;
            float4 x0 = *(const float4*)(rA + k);
            float4 x1 = *(const float4*)(rA + k + 4);
            bfrag f;
            f[0] = (short)f2bf(x0.x); f[1] = (short)f2bf(x0.y);
            f[2] = (short)f2bf(x0.z); f[3] = (short)f2bf(x0.w);
            f[4] = (short)f2bf(x1.x); f[5] = (short)f2bf(x1.y);
            f[6] = (short)f2bf(x1.z); f[7] = (short)f2bf(x1.w);
            wA[ks] = f;
        }
        if (has2) {
            const float* rB = (ntB < 4) ? (Whh + ((size_t)(ntB * 512 + u0 + row15)) * 512)
                                        : (Wgs + (size_t)(u0 + row15) * 512);
#pragma unroll
            for (int ks = 0; ks < 16; ks++) {
                int k = koff + ks * 32;
                float4 x0 = *(const float4*)(rB + k);
                float4 x1 = *(const float4*)(rB + k + 4);
                bfrag f;
                f[0] = (short)f2bf(x0.x); f[1] = (short)f2bf(x0.y);
                f[2] = (short)f2bf(x0.z); f[3] = (short)f2bf(x0.w);
                f[4] = (short)f2bf(x1.x); f[5] = (short)f2bf(x1.y);
                f[6] = (short)f2bf(x1.z); f[7] = (short)f2bf(x1.w);
                wB[ks] = f;
            }
        } else {
#pragma unroll
            for (int ks = 0; ks < 16; ks++) wB[ks] = wA[ks];
        }
    }

    // ---- persistent per-thread state: one unit u = u0 + ul, batch b
    const int u = u0 + ul;
    float h = Hf32[b * HID + u];
    float cc = Cbuf[b * HID + u];
    const int train = *trainPtr;
    const float dmv = train ? dm[b * HID + u] : 1.0f;

    for (int s = 0; s < CH; s++) {
        const int t = c * CH + s;
        const int par = t & 1;
        const int tPhys = rev ? (SEQ - 1 - t) : t;

        // --- prefetch P / mask (independent of h; completes under the poll)
        const float* Pb = P + ((size_t)s * BAT + b) * NG;
        float pi = Pb[u];
        float pf = Pb[512 + u];
        float pg = Pb[1024 + u];
        float po = Pb[1536 + u];
        float pr = Pb[2048 + u];
        float xl = Pb[2560 + u];
        float mk = mask[(size_t)tPhys * BAT + b];

        // --- gather h_t: coalesced tagged loads, poll until tag == t
        {
            const u64* src = Htag + (size_t)par * 8192;
            u64 v[16];
#pragma unroll
            for (int j = 0; j < 16; j++)
                v[j] = __hip_atomic_load(src + j * 512 + tid,
                                         __ATOMIC_RELAXED, __HIP_MEMORY_SCOPE_AGENT);
            const unsigned ex = (unsigned)t;
            while (true) {
                unsigned bad = 0;
#pragma unroll
                for (int j = 0; j < 16; j++) bad |= ((unsigned)(v[j] >> 32)) ^ ex;
                if (!bad) break;
#pragma unroll
                for (int j = 0; j < 16; j++)
                    v[j] = __hip_atomic_load(src + j * 512 + tid,
                                             __ATOMIC_RELAXED, __HIP_MEMORY_SCOPE_AGENT);
            }
            // word j*512+tid = (upair = j*16 + ul, batch b): stage 2 bf16
#pragma unroll
            for (int j = 0; j < 16; j++) {
                int up = j * 16 + ul;
                *(unsigned*)&h_lds[b * LSTR + 2 * up] = (unsigned)v[j];
            }
        }
        __syncthreads();

        // --- MFMA: D[m=batch][n=gate*16+unit_local] = sum_k h[m][k] w[n][k]
        {
            f32x4 acA = {0.f, 0.f, 0.f, 0.f};
            f32x4 acB = {0.f, 0.f, 0.f, 0.f};
            const unsigned short* haA = &h_lds[(mtA * 16 + row15) * LSTR + koff];
            const unsigned short* haB = &h_lds[(mtB * 16 + row15) * LSTR + koff];
#pragma unroll
            for (int ks = 0; ks < 16; ks++) {
                acA = __builtin_amdgcn_mfma_f32_16x16x32_bf16(
                        *(const bfrag*)(haA + ks * 32), wA[ks], acA, 0, 0, 0);
                if (has2)
                    acB = __builtin_amdgcn_mfma_f32_16x16x32_bf16(
                        *(const bfrag*)(haB + ks * 32), wB[ks], acB, 0, 0, 0);
            }
            int mrA = mtA * 16 + (lane >> 4) * 4, clA = ntA * 16 + row15;
#pragma unroll
            for (int r = 0; r < 4; r++) Dst[(mrA + r) * DSTR + clA] = acA[r];
            if (has2) {
                int mrB = mtB * 16 + (lane >> 4) * 4, clB = ntB * 16 + row15;
#pragma unroll
                for (int r = 0; r < 4; r++) Dst[(mrB + r) * DSTR + clB] = acB[r];
            }
        }
        __syncthreads();

        // --- pointwise (fp32): one unit per thread
        float gi = sigf(pi + Dst[b * DSTR + 0  + ul]);
        float gf = sigf(pf + Dst[b * DSTR + 16 + ul]);
        float gg = tanhf(pg + Dst[b * DSTR + 32 + ul]);
        float go = sigf(po + Dst[b * DSTR + 48 + ul]);
        float gr = sigf(pr + Dst[b * DSTR + 64 + ul]);
        float ct = gf * cc + gi * gg;
        float hr_ = go * tanhf(ct);
        float h2 = (gr * hr_ + (1.f - gr) * xl) * dmv;
        float hn = mk * h2 + (1.f - mk) * h;
        cc = mk * ct + (1.f - mk) * cc;
        h = hn;

        // outputs (fire-and-forget)
        if (l == 0) Y[(size_t)t * BAT * HID + b * HID + u] = hn;
        else        out[(size_t)b * SEQ * HID + (size_t)(SEQ - 1 - t) * HID + u] = hn;

        // --- publish h_{t+1}: pack adjacent-unit pair via shfl, coalesced store
        {
            unsigned mybf = (unsigned)f2bf(hn);
            unsigned part = __shfl_xor(mybf, 32, 64);   // partner ul^1, same b
            if (lane < 32) {  // ul even: owns word for upair = (u0>>1) + wv
                u64 pv = (u64)(mybf | (part << 16)) | ((u64)(unsigned)(t + 1) << 32);
                __hip_atomic_store(Htag + (size_t)(par ^ 1) * 8192
                                        + ((size_t)((u0 >> 1) + wv)) * 32 + b,
                                   pv, __ATOMIC_RELAXED, __HIP_MEMORY_SCOPE_AGENT);
            }
        }
    }

    // persist state for next chunk
    Hf32[b * HID + u] = h;
    Cbuf[b * HID + u] = cc;
}

// ---------------------------------------------------------------------------
extern "C" void kernel_launch(void* const* d_in, const int* in_sizes, int n_in,
                              void* d_out, int out_size, void* d_ws, size_t ws_size,
                              hipStream_t stream) {
    const float* x        = (const float*)d_in[0];
    const float* mask     = (const float*)d_in[1];
    const float* W_ih     = (const float*)d_in[2];
    const float* b_ih     = (const float*)d_in[3];
    const float* W_hh     = (const float*)d_in[4];
    const float* b_hh     = (const float*)d_in[5];
    const float* Wg_in    = (const float*)d_in[6];
    const float* bg_in    = (const float*)d_in[7];
    const float* Wg_state = (const float*)d_in[8];
    const float* bg_state = (const float*)d_in[9];
    const float* Wl_in    = (const float*)d_in[10];
    const float* drop     = (const float*)d_in[11];
    const int*   train    = (const int*)d_in[12];
    float* out = (float*)d_out;

    // ws layout:
    //   P     : CH*32*3072 fp32   = 12.58 MB
    //   Y     : 512*32*512 fp32   = 33.55 MB
    //   Htag  : 2*8192 u64        = 128 KB
    //   Hf32  : 32*512 fp32       = 64 KB
    //   Cbuf  : 32*512 fp32       = 64 KB
    float* P    = (float*)d_ws;
    float* Y    = P + (size_t)CH * BAT * NG;
    u64*   Htag = (u64*)(Y + (size_t)SEQ * BAT * HID);
    float* Hf32 = (float*)(Htag + 2 * 8192);
    float* Cbuf = Hf32 + BAT * HID;

    for (int l = 0; l < 2; l++) {
        const int rev = l;
        const float* Wih = W_ih + (size_t)l * 4 * HID * HID;
        const float* Whh = W_hh + (size_t)l * 4 * HID * HID;
        const float* Wgi = Wg_in + (size_t)l * HID * HID;
        const float* Wli = Wl_in + (size_t)l * HID * HID;
        const float* bih = b_ih + (size_t)l * 4 * HID;
        const float* bhh = b_hh + (size_t)l * 4 * HID;
        const float* bgi = bg_in + (size_t)l * HID;
        const float* dm  = drop + (size_t)l * BAT * HID;
        const float* xin = l ? Y : x;

        // zero Htag (tag 0 == expected at t=0, data == h_0 = 0) + Hf32 + Cbuf
        hipMemsetAsync(Htag, 0,
                       (size_t)2 * 8192 * 8 + (size_t)2 * BAT * HID * 4,
                       stream);

        for (int c = 0; c < SEQ / CH; c++) {
            proj_gemm<<<dim3((CH * BAT) / BM, NG / BN), 256, 0, stream>>>(
                xin, c * CH, rev, Wih, Wgi, Wli, bih, bhh, bgi, bg_state, P);
            scan_chunk<<<NB, 512, 0, stream>>>(
                P, Whh, Wg_state, Htag, Hf32, Cbuf, mask, dm, Y, out,
                l, c, train);
        }
    }
}

// Round 6
// 7512.503 us; speedup vs baseline: 1.4155x; 1.0043x over previous
//
#include <hip/hip_runtime.h>
#include <math.h>

#define SEQ 512
#define BAT 32
#define HID 512
#define NG  3072   // 4H gates + H (r) + H (xl)
#define CH  32     // time chunk
#define NB  32     // scan blocks (16 units each)
#define UPB 16     // units per block
#define LSTR 520   // h_lds row stride (bf16 elems, rows 16B-aligned)
#define DSTR 81    // Dst row stride (floats, odd -> conflict-free)

typedef __attribute__((ext_vector_type(8))) short bfrag;
typedef __attribute__((ext_vector_type(4))) float f32x4;
typedef unsigned long long u64;

__device__ __forceinline__ float sigf(float x) { return 1.f / (1.f + expf(-x)); }

__device__ __forceinline__ unsigned short f2bf(float x) {
    unsigned u = __float_as_uint(x);
    return (unsigned short)((u + 0x7fffu + ((u >> 16) & 1u)) >> 16);
}

// ---------------------------------------------------------------------------
// Input projection GEMM (fp32, NT) — unchanged (verified rounds 0-5).
#define BM 64
#define BN 64
#define BK 32
__global__ __launch_bounds__(256) void proj_gemm(
    const float* __restrict__ xin, int t0, int rev,
    const float* __restrict__ Wih, const float* __restrict__ Wgi,
    const float* __restrict__ Wli,
    const float* __restrict__ bih, const float* __restrict__ bhh,
    const float* __restrict__ bgi, const float* __restrict__ bgs,
    float* __restrict__ P)
{
    __shared__ float As[BK][BM + 4];
    __shared__ float Bs[BK][BN + 4];

    const int tid = threadIdx.x;
    const int bm = blockIdx.x;
    const int bn = blockIdx.y;
    const int tx = tid & 15;
    const int ty = tid >> 4;

    float acc[4][4];
#pragma unroll
    for (int i = 0; i < 4; i++)
#pragma unroll
        for (int j = 0; j < 4; j++) acc[i][j] = 0.f;

    for (int k0 = 0; k0 < HID; k0 += BK) {
#pragma unroll
        for (int i = 0; i < 2; i++) {
            int f = tid + i * 256;
            int m = f >> 3, kq = f & 7;
            int gm = bm * 64 + m;
            int t = t0 + (gm >> 5), b = gm & 31;
            int pt = rev ? (SEQ - 1 - t) : t;
            const float* ap = xin + ((size_t)pt * BAT + b) * HID + k0 + kq * 4;
            float4 a4 = *(const float4*)ap;
            As[kq * 4 + 0][m] = a4.x;
            As[kq * 4 + 1][m] = a4.y;
            As[kq * 4 + 2][m] = a4.z;
            As[kq * 4 + 3][m] = a4.w;
        }
#pragma unroll
        for (int i = 0; i < 2; i++) {
            int f = tid + i * 256;
            int n = f >> 3, kq = f & 7;
            int gn = bn * 64 + n;
            const float* wrow = (gn < 2048) ? (Wih + (size_t)gn * HID)
                              : (gn < 2560) ? (Wgi + (size_t)(gn - 2048) * HID)
                                            : (Wli + (size_t)(gn - 2560) * HID);
            float4 b4 = *(const float4*)(wrow + k0 + kq * 4);
            Bs[kq * 4 + 0][n] = b4.x;
            Bs[kq * 4 + 1][n] = b4.y;
            Bs[kq * 4 + 2][n] = b4.z;
            Bs[kq * 4 + 3][n] = b4.w;
        }
        __syncthreads();
#pragma unroll
        for (int k = 0; k < BK; k++) {
            float4 a4 = *(const float4*)&As[k][ty * 4];
            float4 b4 = *(const float4*)&Bs[k][tx * 4];
            float a[4] = {a4.x, a4.y, a4.z, a4.w};
            float b[4] = {b4.x, b4.y, b4.z, b4.w};
#pragma unroll
            for (int i = 0; i < 4; i++)
#pragma unroll
                for (int j = 0; j < 4; j++) acc[i][j] += a[i] * b[j];
        }
        __syncthreads();
    }

    int gnb = bn * 64 + tx * 4;
    float bias[4];
#pragma unroll
    for (int j = 0; j < 4; j++) {
        int gn = gnb + j;
        bias[j] = (gn < 2048) ? (bih[gn] + bhh[gn])
                : (gn < 2560) ? (bgi[gn - 2048] + bgs[gn - 2048])
                              : 0.f;
    }
#pragma unroll
    for (int i = 0; i < 4; i++) {
        int m = bm * 64 + ty * 4 + i;
        float4 o;
        o.x = acc[i][0] + bias[0];
        o.y = acc[i][1] + bias[1];
        o.z = acc[i][2] + bias[2];
        o.w = acc[i][3] + bias[3];
        *(float4*)(P + (size_t)m * NG + gnb) = o;
    }
}

// ---------------------------------------------------------------------------
// Persistent scan. 32 blocks x 512 threads. Reg-resident weights (round 5).
// h exchanged via tagged u64 words {2 bf16 | u32 step tag} in pair-major
// layout Htag[par][upair*32+b]. Poll/publish via EXPLICIT inline-asm
// sc0 sc1 loads/stores: 16 loads batch-issued with immediate offsets, ONE
// s_waitcnt vmcnt(0) + sched_barrier(0) — no per-load serialization, no
// stale-L2 risk. Gather map gives each thread 16 CONSECUTIVE upairs of one
// batch row -> 4x b128 LDS stores.
#define GLD(J, OFF) \
    asm volatile("global_load_dwordx2 %0, %1, off offset:" #OFF " sc0 sc1" \
                 : "=v"(v[J]) : "v"(srcb));
#define GATHER16 \
    GLD(0,0)     GLD(1,256)   GLD(2,512)   GLD(3,768) \
    GLD(4,1024)  GLD(5,1280)  GLD(6,1536)  GLD(7,1792) \
    GLD(8,2048)  GLD(9,2304)  GLD(10,2560) GLD(11,2816) \
    GLD(12,3072) GLD(13,3328) GLD(14,3584) GLD(15,3840)
#define VMWAIT \
    asm volatile("s_waitcnt vmcnt(0)" ::: "memory"); \
    __builtin_amdgcn_sched_barrier(0);

__global__ __launch_bounds__(512, 1) void scan_chunk(
    const float* __restrict__ P,      // [CH][32][3072]
    const float* __restrict__ Whh,    // [2048][512]
    const float* __restrict__ Wgs,    // [512][512]
    u64* __restrict__ Htag,           // [2][8192] tagged words
    float* __restrict__ Hf32,         // [32][512] persist
    float* __restrict__ Cbuf,         // [32][512] persist
    const float* __restrict__ mask,   // [512][32]
    const float* __restrict__ dm,     // [32][512]
    float* __restrict__ Y,            // layer0 out [512][32][512]
    float* __restrict__ out,          // final out [32][512][512]
    int l, int c,
    const int* __restrict__ trainPtr)
{
    __shared__ unsigned short h_lds[BAT * LSTR]; // 33,280 B
    __shared__ float Dst[BAT * DSTR];            // 10,368 B

    const int tid = threadIdx.x;      // 0..511
    const int u0 = blockIdx.x * UPB;
    const int b = tid & 31;
    const int ul = tid >> 5;          // 0..15
    const int lane = tid & 63;
    const int wv = tid >> 6;          // 0..7
    const int rev = (l == 1);
    const int row15 = lane & 15;
    const int koff = (lane >> 4) * 8;

    // ---- wave -> MFMA tile map (as round 5)
    const int mtA = wv / 5, ntA = wv % 5;
    const int has2 = (wv < 2);
    const int mtB = 1, ntB = 3 + wv;

    // ---- load B fragments (once per chunk, bf16): row n = nt*16+row15
    bfrag wA[16], wB[16];
    {
        const float* rA = (ntA < 4) ? (Whh + ((size_t)(ntA * 512 + u0 + row15)) * 512)
                                    : (Wgs + (size_t)(u0 + row15) * 512);
#pragma unroll
        for (int ks = 0; ks < 16; ks++) {
            int k = koff + ks * 32;
            float4 x0 = *(const float4*)(rA + k);
            float4 x1 = *(const float4*)(rA + k + 4);
            bfrag f;
            f[0] = (short)f2bf(x0.x); f[1] = (short)f2bf(x0.y);
            f[2] = (short)f2bf(x0.z); f[3] = (short)f2bf(x0.w);
            f[4] = (short)f2bf(x1.x); f[5] = (short)f2bf(x1.y);
            f[6] = (short)f2bf(x1.z); f[7] = (short)f2bf(x1.w);
            wA[ks] = f;
        }
        if (has2) {
            const float* rB = (ntB < 4) ? (Whh + ((size_t)(ntB * 512 + u0 + row15)) * 512)
                                        : (Wgs + (size_t)(u0 + row15) * 512);
#pragma unroll
            for (int ks = 0; ks < 16; ks++) {
                int k = koff + ks * 32;
                float4 x0 = *(const float4*)(rB + k);
                float4 x1 = *(const float4*)(rB + k + 4);
                bfrag f;
                f[0] = (short)f2bf(x0.x); f[1] = (short)f2bf(x0.y);
                f[2] = (short)f2bf(x0.z); f[3] = (short)f2bf(x0.w);
                f[4] = (short)f2bf(x1.x); f[5] = (short)f2bf(x1.y);
                f[6] = (short)f2bf(x1.z); f[7] = (short)f2bf(x1.w);
                wB[ks] = f;
            }
        } else {
#pragma unroll
            for (int ks = 0; ks < 16; ks++) wB[ks] = wA[ks];
        }
    }

    // ---- persistent per-thread state: one unit u = u0 + ul, batch b
    const int u = u0 + ul;
    float h = Hf32[b * HID + u];
    float cc = Cbuf[b * HID + u];
    const int train = *trainPtr;
    const float dmv = train ? dm[b * HID + u] : 1.0f;

    for (int s = 0; s < CH; s++) {
        const int t = c * CH + s;
        const int par = t & 1;
        const int tPhys = rev ? (SEQ - 1 - t) : t;

        // --- prefetch P / mask (independent of h; completes under the poll)
        const float* Pb = P + ((size_t)s * BAT + b) * NG;
        float pi = Pb[u];
        float pf = Pb[512 + u];
        float pg = Pb[1024 + u];
        float po = Pb[1536 + u];
        float pr = Pb[2048 + u];
        float xl = Pb[2560 + u];
        float mk = mask[(size_t)tPhys * BAT + b];

        // --- gather h_t: thread reads upairs ul*16..ul*16+15 of batch row b
        //     (word idx = (ul*16+j)*32 + b = ul*512 + j*32 + b; byte off j*256)
        {
            const u64* srcb = Htag + (size_t)par * 8192 + (size_t)ul * 512 + b;
            u64 v[16];
            GATHER16
            VMWAIT
            const unsigned ex = (unsigned)t;
            while (true) {
                unsigned bad = 0;
#pragma unroll
                for (int j = 0; j < 16; j++)
                    bad |= ((unsigned)(v[j] >> 32)) ^ ex;
                if (!bad) break;
                GATHER16
                VMWAIT
            }
            // stage: 4x b128 stores, elems 2*(ul*16+4q)..+7 of row b
#pragma unroll
            for (int q = 0; q < 4; q++) {
                uint4 wq;
                wq.x = (unsigned)v[4 * q + 0];
                wq.y = (unsigned)v[4 * q + 1];
                wq.z = (unsigned)v[4 * q + 2];
                wq.w = (unsigned)v[4 * q + 3];
                *(uint4*)&h_lds[b * LSTR + (ul * 16 + 4 * q) * 2] = wq;
            }
        }
        __syncthreads();

        // --- MFMA: D[m=batch][n=gate*16+unit_local] = sum_k h[m][k] w[n][k]
        {
            f32x4 acA = {0.f, 0.f, 0.f, 0.f};
            f32x4 acB = {0.f, 0.f, 0.f, 0.f};
            const unsigned short* haA = &h_lds[(mtA * 16 + row15) * LSTR + koff];
            const unsigned short* haB = &h_lds[(mtB * 16 + row15) * LSTR + koff];
#pragma unroll
            for (int ks = 0; ks < 16; ks++) {
                acA = __builtin_amdgcn_mfma_f32_16x16x32_bf16(
                        *(const bfrag*)(haA + ks * 32), wA[ks], acA, 0, 0, 0);
                if (has2)
                    acB = __builtin_amdgcn_mfma_f32_16x16x32_bf16(
                        *(const bfrag*)(haB + ks * 32), wB[ks], acB, 0, 0, 0);
            }
            int mrA = mtA * 16 + (lane >> 4) * 4, clA = ntA * 16 + row15;
#pragma unroll
            for (int r = 0; r < 4; r++) Dst[(mrA + r) * DSTR + clA] = acA[r];
            if (has2) {
                int mrB = mtB * 16 + (lane >> 4) * 4, clB = ntB * 16 + row15;
#pragma unroll
                for (int r = 0; r < 4; r++) Dst[(mrB + r) * DSTR + clB] = acB[r];
            }
        }
        __syncthreads();

        // --- pointwise (fp32): one unit per thread
        float gi = sigf(pi + Dst[b * DSTR + 0  + ul]);
        float gf = sigf(pf + Dst[b * DSTR + 16 + ul]);
        float gg = tanhf(pg + Dst[b * DSTR + 32 + ul]);
        float go = sigf(po + Dst[b * DSTR + 48 + ul]);
        float gr = sigf(pr + Dst[b * DSTR + 64 + ul]);
        float ct = gf * cc + gi * gg;
        float hr_ = go * tanhf(ct);
        float h2 = (gr * hr_ + (1.f - gr) * xl) * dmv;
        float hn = mk * h2 + (1.f - mk) * h;
        cc = mk * ct + (1.f - mk) * cc;
        h = hn;

        // --- publish h_{t+1} FIRST (critical path), then outputs
        {
            unsigned mybf = (unsigned)f2bf(hn);
            unsigned part = __shfl_xor(mybf, 32, 64);   // partner ul^1, same b
            if (lane < 32) {  // ul even: owns word for upair = (u0>>1) + wv
                u64 pv = (u64)(mybf | (part << 16)) | ((u64)(unsigned)(t + 1) << 32);
                u64* dst = Htag + (size_t)(par ^ 1) * 8192
                                + ((size_t)((u0 >> 1) + wv)) * 32 + b;
                asm volatile("global_store_dwordx2 %0, %1, off sc0 sc1"
                             :: "v"(dst), "v"(pv) : "memory");
            }
        }
        if (l == 0) Y[(size_t)t * BAT * HID + b * HID + u] = hn;
        else        out[(size_t)b * SEQ * HID + (size_t)(SEQ - 1 - t) * HID + u] = hn;
    }

    // persist state for next chunk
    Hf32[b * HID + u] = h;
    Cbuf[b * HID + u] = cc;
}

// ---------------------------------------------------------------------------
extern "C" void kernel_launch(void* const* d_in, const int* in_sizes, int n_in,
                              void* d_out, int out_size, void* d_ws, size_t ws_size,
                              hipStream_t stream) {
    const float* x        = (const float*)d_in[0];
    const float* mask     = (const float*)d_in[1];
    const float* W_ih     = (const float*)d_in[2];
    const float* b_ih     = (const float*)d_in[3];
    const float* W_hh     = (const float*)d_in[4];
    const float* b_hh     = (const float*)d_in[5];
    const float* Wg_in    = (const float*)d_in[6];
    const float* bg_in    = (const float*)d_in[7];
    const float* Wg_state = (const float*)d_in[8];
    const float* bg_state = (const float*)d_in[9];
    const float* Wl_in    = (const float*)d_in[10];
    const float* drop     = (const float*)d_in[11];
    const int*   train    = (const int*)d_in[12];
    float* out = (float*)d_out;

    // ws layout:
    //   P     : CH*32*3072 fp32   = 12.58 MB
    //   Y     : 512*32*512 fp32   = 33.55 MB
    //   Htag  : 2*8192 u64        = 128 KB
    //   Hf32  : 32*512 fp32       = 64 KB
    //   Cbuf  : 32*512 fp32       = 64 KB
    float* P    = (float*)d_ws;
    float* Y    = P + (size_t)CH * BAT * NG;
    u64*   Htag = (u64*)(Y + (size_t)SEQ * BAT * HID);
    float* Hf32 = (float*)(Htag + 2 * 8192);
    float* Cbuf = Hf32 + BAT * HID;

    for (int l = 0; l < 2; l++) {
        const int rev = l;
        const float* Wih = W_ih + (size_t)l * 4 * HID * HID;
        const float* Whh = W_hh + (size_t)l * 4 * HID * HID;
        const float* Wgi = Wg_in + (size_t)l * HID * HID;
        const float* Wli = Wl_in + (size_t)l * HID * HID;
        const float* bih = b_ih + (size_t)l * 4 * HID;
        const float* bhh = b_hh + (size_t)l * 4 * HID;
        const float* bgi = bg_in + (size_t)l * HID;
        const float* dm  = drop + (size_t)l * BAT * HID;
        const float* xin = l ? Y : x;

        // zero Htag (tag 0 == expected at t=0, data == h_0 = 0) + Hf32 + Cbuf
        hipMemsetAsync(Htag, 0,
                       (size_t)2 * 8192 * 8 + (size_t)2 * BAT * HID * 4,
                       stream);

        for (int c = 0; c < SEQ / CH; c++) {
            proj_gemm<<<dim3((CH * BAT) / BM, NG / BN), 256, 0, stream>>>(
                xin, c * CH, rev, Wih, Wgi, Wli, bih, bhh, bgi, bg_state, P);
            scan_chunk<<<NB, 512, 0, stream>>>(
                P, Whh, Wg_state, Htag, Hf32, Cbuf, mask, dm, Y, out,
                l, c, train);
        }
    }
}

// Round 10
// 4853.501 us; speedup vs baseline: 2.1910x; 1.5479x over previous
//
#include <hip/hip_runtime.h>
#include <math.h>

#define SEQ 512
#define BAT 32
#define HID 512
#define NG  3072   // 4H gates + H (r) + H (xl)
#define CH  32     // time chunk
#define NB  32     // scan blocks (16 units each)
#define UPB 16     // units per block
#define DSTR 81    // Dst row stride (floats, odd -> conflict-free)
#define HOSTR 20   // hout row stride (floats, 16B-aligned rows, spread banks)
#define PASTR 72   // proj LDS tile row stride (bf16 elems, 64+8)

typedef __attribute__((ext_vector_type(8))) short bfrag;
typedef __attribute__((ext_vector_type(4))) float f32x4;
typedef unsigned long long u64;

__device__ __forceinline__ float sigf(float x) { return 1.f / (1.f + expf(-x)); }

__device__ __forceinline__ unsigned short f2bf(float x) {
    unsigned u = __float_as_uint(x);
    return (unsigned short)((u + 0x7fffu + ((u >> 16) & 1u)) >> 16);
}
__device__ __forceinline__ unsigned pk2(float a, float b) {
    return (unsigned)f2bf(a) | ((unsigned)f2bf(b) << 16);
}

// ---------------------------------------------------------------------------
// Input projection GEMM, bf16 MFMA (fp32 accumulate, fp32 bias epilogue).
// C tile 64x64, K staged 64 at a time as bf16 in LDS. Fragment convention
// identical to the scan kernel (verified rounds 1-6): A row = lane&15 (M),
// B row = lane&15 (N), k = (lane>>4)*8 + ks*32 + 0..7; D row = (lane>>4)*4+r.
// Output written TRANSPOSED: Pt[tl][n][b] so the scan's P loads coalesce.
__global__ __launch_bounds__(256) void proj_gemm(
    const float* __restrict__ xin, int t0, int rev,
    const float* __restrict__ Wih, const float* __restrict__ Wgi,
    const float* __restrict__ Wli,
    const float* __restrict__ bih, const float* __restrict__ bhh,
    const float* __restrict__ bgi, const float* __restrict__ bgs,
    float* __restrict__ Pt)           // [CH][NG][BAT]
{
    __shared__ unsigned short As[64 * PASTR];  // 9,216 B
    __shared__ unsigned short Bs[64 * PASTR];  // 9,216 B

    const int tid = threadIdx.x;
    const int bm = blockIdx.x;        // 16 M-tiles (CH*BAT/64)
    const int bn = blockIdx.y;        // 48 N-tiles
    const int lane = tid & 63, wv = tid >> 6;
    const int row15 = lane & 15, koff8 = (lane >> 4) * 8;

    f32x4 acc[4];
#pragma unroll
    for (int i = 0; i < 4; i++) acc[i] = (f32x4){0.f, 0.f, 0.f, 0.f};

    // staging map: thread -> (row r, k-quarter q); 16 consecutive floats
    const int r = tid >> 2, q = tid & 3;
    const int gm = bm * 64 + r;
    const int tt = t0 + (gm >> 5), bb = gm & 31;
    const int pt = rev ? (SEQ - 1 - tt) : tt;
    const float* arow = xin + ((size_t)pt * BAT + bb) * HID;
    const int gn = bn * 64 + r;
    const float* brow = (gn < 2048) ? (Wih + (size_t)gn * HID)
                      : (gn < 2560) ? (Wgi + (size_t)(gn - 2048) * HID)
                                    : (Wli + (size_t)(gn - 2560) * HID);

    for (int k0 = 0; k0 < HID; k0 += 64) {
        {
            const float* ap = arow + k0 + q * 16;
            float4 v0 = ((const float4*)ap)[0];
            float4 v1 = ((const float4*)ap)[1];
            float4 v2 = ((const float4*)ap)[2];
            float4 v3 = ((const float4*)ap)[3];
            uint4 w0 = { pk2(v0.x,v0.y), pk2(v0.z,v0.w), pk2(v1.x,v1.y), pk2(v1.z,v1.w) };
            uint4 w1 = { pk2(v2.x,v2.y), pk2(v2.z,v2.w), pk2(v3.x,v3.y), pk2(v3.z,v3.w) };
            *(uint4*)&As[r * PASTR + q * 16]     = w0;
            *(uint4*)&As[r * PASTR + q * 16 + 8] = w1;
            const float* bp = brow + k0 + q * 16;
            v0 = ((const float4*)bp)[0];
            v1 = ((const float4*)bp)[1];
            v2 = ((const float4*)bp)[2];
            v3 = ((const float4*)bp)[3];
            uint4 x0 = { pk2(v0.x,v0.y), pk2(v0.z,v0.w), pk2(v1.x,v1.y), pk2(v1.z,v1.w) };
            uint4 x1 = { pk2(v2.x,v2.y), pk2(v2.z,v2.w), pk2(v3.x,v3.y), pk2(v3.z,v3.w) };
            *(uint4*)&Bs[r * PASTR + q * 16]     = x0;
            *(uint4*)&Bs[r * PASTR + q * 16 + 8] = x1;
        }
        __syncthreads();
        const unsigned short* ha = &As[(wv * 16 + row15) * PASTR + koff8];
#pragma unroll
        for (int ks = 0; ks < 2; ks++) {
            bfrag a = *(const bfrag*)(ha + ks * 32);
#pragma unroll
            for (int nt = 0; nt < 4; nt++) {
                bfrag bf = *(const bfrag*)(&Bs[(nt * 16 + row15) * PASTR + koff8 + ks * 32]);
                acc[nt] = __builtin_amdgcn_mfma_f32_16x16x32_bf16(a, bf, acc[nt], 0, 0, 0);
            }
        }
        __syncthreads();
    }

    // epilogue: D rows m = wv*16 + (lane>>4)*4 + r  ->  (tl = gm>>5, b = gm&31)
    // b0 % 4 == 0 and the 4 r's stay in one tl -> contiguous float4 in Pt.
    const int ml = wv * 16 + (lane >> 4) * 4;
    const int gm2 = bm * 64 + ml;
    const int tl = gm2 >> 5, b0 = gm2 & 31;
#pragma unroll
    for (int nt = 0; nt < 4; nt++) {
        int gn2 = bn * 64 + nt * 16 + row15;
        float bias = (gn2 < 2048) ? (bih[gn2] + bhh[gn2])
                   : (gn2 < 2560) ? (bgi[gn2 - 2048] + bgs[gn2 - 2048])
                                  : 0.f;
        float4 o = { acc[nt][0] + bias, acc[nt][1] + bias,
                     acc[nt][2] + bias, acc[nt][3] + bias };
        *(float4*)&Pt[((size_t)tl * NG + gn2) * BAT + b0] = o;
    }
}

// ---------------------------------------------------------------------------
// Persistent scan (r6 skeleton, proven). 32 blocks x 512 threads, reg-resident
// weights, tag-in-word h exchange {2 bf16 | u32 step tag} via sc0 sc1 asm.
// This round: conflict-free h16 LDS layout [ks][granule][batch]; P loads
// moved OUT of the poll's vmcnt scope (coalesced via transposed Pt); output
// stores coalesced through a padded LDS transpose.
#define GLD(J, OFF) \
    asm volatile("global_load_dwordx2 %0, %1, off offset:" #OFF " sc0 sc1" \
                 : "=v"(v[J]) : "v"(srcb));
#define GATHER16 \
    GLD(0,0)     GLD(1,256)   GLD(2,512)   GLD(3,768) \
    GLD(4,1024)  GLD(5,1280)  GLD(6,1536)  GLD(7,1792) \
    GLD(8,2048)  GLD(9,2304)  GLD(10,2560) GLD(11,2816) \
    GLD(12,3072) GLD(13,3328) GLD(14,3584) GLD(15,3840)
#define VMWAIT \
    asm volatile("s_waitcnt vmcnt(0)" ::: "memory"); \
    __builtin_amdgcn_sched_barrier(0);

__global__ __launch_bounds__(512, 1) void scan_chunk(
    const float* __restrict__ Pt,     // [CH][NG][BAT] transposed
    const float* __restrict__ Whh,    // [2048][512]
    const float* __restrict__ Wgs,    // [512][512]
    u64* __restrict__ Htag,           // [2][8192] tagged words
    float* __restrict__ Hf32,         // [32][512] persist
    float* __restrict__ Cbuf,         // [32][512] persist
    const float* __restrict__ mask,   // [512][32]
    const float* __restrict__ dm,     // [32][512]
    float* __restrict__ Y,            // layer0 out [512][32][512]
    float* __restrict__ out,          // final out [32][512][512]
    int l, int c,
    const int* __restrict__ trainPtr)
{
    __shared__ uint4 h16[16 * 4 * 32];     // 32 KB: [ks][g][b] 16B granules
    __shared__ float Dst[BAT * DSTR];      // 10.4 KB
    __shared__ float hout[BAT * HOSTR];    //  2.5 KB

    const int tid = threadIdx.x;      // 0..511
    const int u0 = blockIdx.x * UPB;
    const int b = tid & 31;
    const int ul = tid >> 5;          // 0..15
    const int lane = tid & 63;
    const int wv = tid >> 6;          // 0..7
    const int rev = (l == 1);
    const int row15 = lane & 15;
    const int koff = (lane >> 4) * 8;

    // ---- wave -> MFMA tile map (verified r5/r6)
    const int mtA = wv / 5, ntA = wv % 5;
    const int has2 = (wv < 2);
    const int mtB = 1, ntB = 3 + wv;

    // ---- load B fragments (once per chunk, bf16): row n = nt*16+row15
    bfrag wA[16], wB[16];
    {
        const float* rA = (ntA < 4) ? (Whh + ((size_t)(ntA * 512 + u0 + row15)) * 512)
                                    : (Wgs + (size_t)(u0 + row15) * 512);
#pragma unroll
        for (int ks = 0; ks < 16; ks++) {
            int k = koff + ks * 32;
            float4 x0 = *(const float4*)(rA + k);
            float4 x1 = *(const float4*)(rA + k + 4);
            bfrag f;
            f[0] = (short)f2bf(x0.x); f[1] = (short)f2bf(x0.y);
            f[2] = (short)f2bf(x0.z); f[3] = (short)f2bf(x0.w);
            f[4] = (short)f2bf(x1.x); f[5] = (short)f2bf(x1.y);
            f[6] = (short)f2bf(x1.z); f[7] = (short)f2bf(x1.w);
            wA[ks] = f;
        }
        if (has2) {
            const float* rB = (ntB < 4) ? (Whh + ((size_t)(ntB * 512 + u0 + row15)) * 512)
                                        : (Wgs + (size_t)(u0 + row15) * 512);
#pragma unroll
            for (int ks = 0; ks < 16; ks++) {
                int k = koff + ks * 32;
                float4 x0 = *(const float4*)(rB + k);
                float4 x1 = *(const float4*)(rB + k + 4);
                bfrag f;
                f[0] = (short)f2bf(x0.x); f[1] = (short)f2bf(x0.y);
                f[2] = (short)f2bf(x0.z); f[3] = (short)f2bf(x0.w);
                f[4] = (short)f2bf(x1.x); f[5] = (short)f2bf(x1.y);
                f[6] = (short)f2bf(x1.z); f[7] = (short)f2bf(x1.w);
                wB[ks] = f;
            }
        } else {
#pragma unroll
            for (int ks = 0; ks < 16; ks++) wB[ks] = wA[ks];
        }
    }

    // ---- persistent per-thread state: one unit u = u0 + ul, batch b
    const int u = u0 + ul;
    float h = Hf32[b * HID + u];
    float cc = Cbuf[b * HID + u];
    const int train = *trainPtr;
    const float dmv = train ? dm[b * HID + u] : 1.0f;

    // MFMA A-operand read pointers into h16 (conflict-free layout):
    // element (batch bb, k = ks*32 + g*8 + e) at byte ks*2048 + g*512 + bb*16
    const char* hb = (const char*)h16;
    const char* haA = hb + (size_t)(lane >> 4) * 512 + (mtA * 16 + row15) * 16;
    const char* haB = hb + (size_t)(lane >> 4) * 512 + (mtB * 16 + row15) * 16;

    for (int s = 0; s < CH; s++) {
        const int t = c * CH + s;
        const int par = t & 1;
        const int tPhys = rev ? (SEQ - 1 - t) : t;

        // --- gather h_t: ONLY gather loads inside the vmcnt(0) scope
        {
            const u64* srcb = Htag + (size_t)par * 8192 + (size_t)ul * 512 + b;
            u64 v[16];
            GATHER16
            VMWAIT
            const unsigned ex = (unsigned)t;
            while (true) {
                unsigned bad = 0;
#pragma unroll
                for (int j = 0; j < 16; j++)
                    bad |= ((unsigned)(v[j] >> 32)) ^ ex;
                if (!bad) break;
                GATHER16
                VMWAIT
            }
            // stage: thread holds units ul*32 .. ul*32+31 of batch b
            //        -> k-granules (ks=ul, g=q) at h16[(ul*4+q)*32 + b]
#pragma unroll
            for (int q = 0; q < 4; q++) {
                uint4 wq;
                wq.x = (unsigned)v[4 * q + 0];
                wq.y = (unsigned)v[4 * q + 1];
                wq.z = (unsigned)v[4 * q + 2];
                wq.w = (unsigned)v[4 * q + 3];
                h16[(ul * 4 + q) * 32 + b] = wq;
            }
        }

        // --- P / mask loads (coalesced; latency hidden under stage+MFMA)
        const float* Pb = Pt + (size_t)s * NG * BAT;
        float pi = Pb[(size_t)(0 * HID + u) * BAT + b];
        float pf = Pb[(size_t)(1 * HID + u) * BAT + b];
        float pg = Pb[(size_t)(2 * HID + u) * BAT + b];
        float po = Pb[(size_t)(3 * HID + u) * BAT + b];
        float pr = Pb[(size_t)(4 * HID + u) * BAT + b];
        float xl = Pb[(size_t)(5 * HID + u) * BAT + b];
        float mk = mask[(size_t)tPhys * BAT + b];
        __syncthreads();

        // --- MFMA: D[m=batch][n=gate*16+unit_local] = sum_k h[m][k] w[n][k]
        {
            f32x4 acA = {0.f, 0.f, 0.f, 0.f};
            f32x4 acB = {0.f, 0.f, 0.f, 0.f};
#pragma unroll
            for (int ks = 0; ks < 16; ks++) {
                acA = __builtin_amdgcn_mfma_f32_16x16x32_bf16(
                        *(const bfrag*)(haA + (size_t)ks * 2048), wA[ks], acA, 0, 0, 0);
                if (has2)
                    acB = __builtin_amdgcn_mfma_f32_16x16x32_bf16(
                        *(const bfrag*)(haB + (size_t)ks * 2048), wB[ks], acB, 0, 0, 0);
            }
            int mrA = mtA * 16 + (lane >> 4) * 4, clA = ntA * 16 + row15;
#pragma unroll
            for (int r = 0; r < 4; r++) Dst[(mrA + r) * DSTR + clA] = acA[r];
            if (has2) {
                int mrB = mtB * 16 + (lane >> 4) * 4, clB = ntB * 16 + row15;
#pragma unroll
                for (int r = 0; r < 4; r++) Dst[(mrB + r) * DSTR + clB] = acB[r];
            }
        }
        __syncthreads();

        // --- pointwise (fp32): one unit per thread
        float gi = sigf(pi + Dst[b * DSTR + 0  + ul]);
        float gf = sigf(pf + Dst[b * DSTR + 16 + ul]);
        float gg = tanhf(pg + Dst[b * DSTR + 32 + ul]);
        float go = sigf(po + Dst[b * DSTR + 48 + ul]);
        float gr = sigf(pr + Dst[b * DSTR + 64 + ul]);
        float ct = gf * cc + gi * gg;
        float hr_ = go * tanhf(ct);
        float h2 = (gr * hr_ + (1.f - gr) * xl) * dmv;
        float hn = mk * h2 + (1.f - mk) * h;
        cc = mk * ct + (1.f - mk) * cc;
        h = hn;

        // --- publish h_{t+1} FIRST (critical path)
        {
            unsigned mybf = (unsigned)f2bf(hn);
            unsigned part = __shfl_xor(mybf, 32, 64);   // partner ul^1, same b
            if (lane < 32) {  // ul even: owns word for upair = blockIdx.x*8+wv
                u64 pv = (u64)(mybf | (part << 16)) | ((u64)(unsigned)(t + 1) << 32);
                u64* dst = Htag + (size_t)(par ^ 1) * 8192
                                + ((size_t)(blockIdx.x * 8 + wv)) * 32 + b;
                asm volatile("global_store_dwordx2 %0, %1, off sc0 sc1"
                             :: "v"(dst), "v"(pv) : "memory");
            }
        }

        // --- coalesced output: transpose through padded LDS, 64B-line stores
        hout[b * HOSTR + ul] = hn;
        __syncthreads();
        if (tid < 128) {
            int bb = tid >> 2, q = tid & 3;
            float4 o = *(const float4*)&hout[bb * HOSTR + 4 * q];
            if (l == 0)
                *(float4*)&Y[(size_t)t * BAT * HID + bb * HID + u0 + 4 * q] = o;
            else
                *(float4*)&out[(size_t)bb * SEQ * HID
                               + (size_t)(SEQ - 1 - t) * HID + u0 + 4 * q] = o;
        }
    }

    // persist state for next chunk
    Hf32[b * HID + u] = h;
    Cbuf[b * HID + u] = cc;
}

// ---------------------------------------------------------------------------
extern "C" void kernel_launch(void* const* d_in, const int* in_sizes, int n_in,
                              void* d_out, int out_size, void* d_ws, size_t ws_size,
                              hipStream_t stream) {
    const float* x        = (const float*)d_in[0];
    const float* mask     = (const float*)d_in[1];
    const float* W_ih     = (const float*)d_in[2];
    const float* b_ih     = (const float*)d_in[3];
    const float* W_hh     = (const float*)d_in[4];
    const float* b_hh     = (const float*)d_in[5];
    const float* Wg_in    = (const float*)d_in[6];
    const float* bg_in    = (const float*)d_in[7];
    const float* Wg_state = (const float*)d_in[8];
    const float* bg_state = (const float*)d_in[9];
    const float* Wl_in    = (const float*)d_in[10];
    const float* drop     = (const float*)d_in[11];
    const int*   train    = (const int*)d_in[12];
    float* out = (float*)d_out;

    // ws layout:
    //   Pt    : CH*3072*32 fp32   = 12.58 MB (transposed [tl][n][b])
    //   Y     : 512*32*512 fp32   = 33.55 MB
    //   Htag  : 2*8192 u64        = 128 KB
    //   Hf32  : 32*512 fp32       = 64 KB
    //   Cbuf  : 32*512 fp32       = 64 KB
    float* Pt   = (float*)d_ws;
    float* Y    = Pt + (size_t)CH * NG * BAT;
    u64*   Htag = (u64*)(Y + (size_t)SEQ * BAT * HID);
    float* Hf32 = (float*)(Htag + 2 * 8192);
    float* Cbuf = Hf32 + BAT * HID;

    for (int l = 0; l < 2; l++) {
        const int rev = l;
        const float* Wih = W_ih + (size_t)l * 4 * HID * HID;
        const float* Whh = W_hh + (size_t)l * 4 * HID * HID;
        const float* Wgi = Wg_in + (size_t)l * HID * HID;
        const float* Wli = Wl_in + (size_t)l * HID * HID;
        const float* bih = b_ih + (size_t)l * 4 * HID;
        const float* bhh = b_hh + (size_t)l * 4 * HID;
        const float* bgi = bg_in + (size_t)l * HID;
        const float* dm  = drop + (size_t)l * BAT * HID;
        const float* xin = l ? Y : x;

        // zero Htag (tag 0 == expected at t=0, data == h_0 = 0) + Hf32 + Cbuf
        hipMemsetAsync(Htag, 0,
                       (size_t)2 * 8192 * 8 + (size_t)2 * BAT * HID * 4,
                       stream);

        for (int c = 0; c < SEQ / CH; c++) {
            proj_gemm<<<dim3((CH * BAT) / 64, NG / 64), 256, 0, stream>>>(
                xin, c * CH, rev, Wih, Wgi, Wli, bih, bhh, bgi, bg_state, Pt);
            scan_chunk<<<NB, 512, 0, stream>>>(
                Pt, Whh, Wg_state, Htag, Hf32, Cbuf, mask, dm, Y, out,
                l, c, train);
        }
    }
}

// Round 11
// 3986.407 us; speedup vs baseline: 2.6676x; 1.2175x over previous
//
#include <hip/hip_runtime.h>
#include <math.h>

#define SEQ 512
#define BAT 32
#define HID 512
#define NG  3072   // 4H gates + H (r) + H (xl)
#define CH  32     // time chunk
#define NB  32     // scan blocks (16 units each)
#define UPB 16     // units per block
#define DSTR 81    // Dst row stride (floats, odd -> conflict-free)
#define HOSTR 20   // hout row stride
#define PASTR 72   // proj LDS row stride (bf16 elems, 64+8)
#define NPROJB 192 // fused proj blocks (2 jobs each, 384 jobs)

typedef __attribute__((ext_vector_type(8))) short bfrag;
typedef __attribute__((ext_vector_type(4))) float f32x4;
typedef unsigned long long u64;

__device__ __forceinline__ float sigf(float x) { return 1.f / (1.f + expf(-x)); }

__device__ __forceinline__ unsigned short f2bf(float x) {
    unsigned u = __float_as_uint(x);
    return (unsigned short)((u + 0x7fffu + ((u >> 16) & 1u)) >> 16);
}
__device__ __forceinline__ unsigned pk2(float a, float b) {
    return (unsigned)f2bf(a) | ((unsigned)f2bf(b) << 16);
}
__device__ __forceinline__ float bf2f(unsigned short s) {
    return __uint_as_float((unsigned)s << 16);
}

// ---------------------------------------------------------------------------
// Projection tile job: 128(M) x 64(N), 512 threads (8 waves), bf16 MFMA,
// fp32 accumulate + bias, bf16 output Pt[tl][n][b]. Job id jd in [0,384):
// bm = jd&7 (M), bn = jd>>3 (N). Fragment convention as verified r10.
__device__ __forceinline__ void proj_tile(
    int jd, const float* __restrict__ xin, int t0, int rev,
    const float* __restrict__ Wih, const float* __restrict__ Wgi,
    const float* __restrict__ Wli,
    const float* __restrict__ bih, const float* __restrict__ bhh,
    const float* __restrict__ bgi, const float* __restrict__ bgs,
    unsigned short* __restrict__ Pt,
    unsigned short* As, unsigned short* Bs, int tid)
{
    const int bm = jd & 7, bn = jd >> 3;
    const int lane = tid & 63, wv = tid >> 6;
    const int row15 = lane & 15, koff8 = (lane >> 4) * 8;

    f32x4 acc[4];
#pragma unroll
    for (int i = 0; i < 4; i++) acc[i] = (f32x4){0.f, 0.f, 0.f, 0.f};

    const int r = tid >> 2, q = tid & 3;       // A: r 0..127
    const int gm = bm * 128 + r;
    const int tt = t0 + (gm >> 5), bb = gm & 31;
    const int pt = rev ? (SEQ - 1 - tt) : tt;
    const float* arow = xin + ((size_t)pt * BAT + bb) * HID;

    const float* brow = nullptr;
    if (tid < 256) {                           // B: r 0..63 (tid>>2)
        const int gn = bn * 64 + r;
        brow = (gn < 2048) ? (Wih + (size_t)gn * HID)
             : (gn < 2560) ? (Wgi + (size_t)(gn - 2048) * HID)
                           : (Wli + (size_t)(gn - 2560) * HID);
    }

    for (int k0 = 0; k0 < HID; k0 += 64) {
        {
            const float* ap = arow + k0 + q * 16;
            float4 v0 = ((const float4*)ap)[0];
            float4 v1 = ((const float4*)ap)[1];
            float4 v2 = ((const float4*)ap)[2];
            float4 v3 = ((const float4*)ap)[3];
            uint4 w0 = { pk2(v0.x,v0.y), pk2(v0.z,v0.w), pk2(v1.x,v1.y), pk2(v1.z,v1.w) };
            uint4 w1 = { pk2(v2.x,v2.y), pk2(v2.z,v2.w), pk2(v3.x,v3.y), pk2(v3.z,v3.w) };
            *(uint4*)&As[r * PASTR + q * 16]     = w0;
            *(uint4*)&As[r * PASTR + q * 16 + 8] = w1;
            if (tid < 256) {
                const float* bp = brow + k0 + q * 16;
                v0 = ((const float4*)bp)[0];
                v1 = ((const float4*)bp)[1];
                v2 = ((const float4*)bp)[2];
                v3 = ((const float4*)bp)[3];
                uint4 x0 = { pk2(v0.x,v0.y), pk2(v0.z,v0.w), pk2(v1.x,v1.y), pk2(v1.z,v1.w) };
                uint4 x1 = { pk2(v2.x,v2.y), pk2(v2.z,v2.w), pk2(v3.x,v3.y), pk2(v3.z,v3.w) };
                *(uint4*)&Bs[r * PASTR + q * 16]     = x0;
                *(uint4*)&Bs[r * PASTR + q * 16 + 8] = x1;
            }
        }
        __syncthreads();
        const unsigned short* ha = &As[(wv * 16 + row15) * PASTR + koff8];
#pragma unroll
        for (int ks = 0; ks < 2; ks++) {
            bfrag a = *(const bfrag*)(ha + ks * 32);
#pragma unroll
            for (int nt = 0; nt < 4; nt++) {
                bfrag bf = *(const bfrag*)(&Bs[(nt * 16 + row15) * PASTR + koff8 + ks * 32]);
                acc[nt] = __builtin_amdgcn_mfma_f32_16x16x32_bf16(a, bf, acc[nt], 0, 0, 0);
            }
        }
        __syncthreads();
    }

    const int ml = wv * 16 + ((lane >> 4) << 2);
    const int gm2 = bm * 128 + ml;
    const int tl = gm2 >> 5, b0 = gm2 & 31;
#pragma unroll
    for (int nt = 0; nt < 4; nt++) {
        int gn2 = bn * 64 + nt * 16 + row15;
        float bias = (gn2 < 2048) ? (bih[gn2] + bhh[gn2])
                   : (gn2 < 2560) ? (bgi[gn2 - 2048] + bgs[gn2 - 2048])
                                  : 0.f;
        uint2 o = { pk2(acc[nt][0] + bias, acc[nt][1] + bias),
                    pk2(acc[nt][2] + bias, acc[nt][3] + bias) };
        *(uint2*)&Pt[((size_t)tl * NG + gn2) * BAT + b0] = o;
    }
}

// standalone projection (chunk 0 of each layer): 384 jobs, 1 per block
__global__ __launch_bounds__(512) void proj_gemm(
    const float* __restrict__ xin, int t0, int rev,
    const float* __restrict__ Wih, const float* __restrict__ Wgi,
    const float* __restrict__ Wli,
    const float* __restrict__ bih, const float* __restrict__ bhh,
    const float* __restrict__ bgi, const float* __restrict__ bgs,
    unsigned short* __restrict__ Pt)
{
    __shared__ unsigned short As[128 * PASTR];
    __shared__ unsigned short Bs[64 * PASTR];
    proj_tile(blockIdx.x, xin, t0, rev, Wih, Wgi, Wli, bih, bhh, bgi, bgs,
              Pt, As, Bs, threadIdx.x);
}

// ---------------------------------------------------------------------------
// Fused persistent scan + next-chunk projection.
// Blocks 0..31: scan chunk c from PtR (tag-in-word h exchange, proven r10).
// Blocks 32..223: projection of chunk c+1 into PtW (2 jobs each), then exit.
#define GLD(J, OFF) \
    asm volatile("global_load_dwordx2 %0, %1, off offset:" #OFF " sc0 sc1" \
                 : "=v"(v[J]) : "v"(srcb));
#define GATHER16 \
    GLD(0,0)     GLD(1,256)   GLD(2,512)   GLD(3,768) \
    GLD(4,1024)  GLD(5,1280)  GLD(6,1536)  GLD(7,1792) \
    GLD(8,2048)  GLD(9,2304)  GLD(10,2560) GLD(11,2816) \
    GLD(12,3072) GLD(13,3328) GLD(14,3584) GLD(15,3840)
#define VMWAIT \
    asm volatile("s_waitcnt vmcnt(0)" ::: "memory"); \
    __builtin_amdgcn_sched_barrier(0);

__global__ __launch_bounds__(512, 1) void scan_chunk(
    const unsigned short* __restrict__ PtR,  // [CH][NG][BAT] bf16
    const float* __restrict__ Whh,
    const float* __restrict__ Wgs,
    u64* __restrict__ Htag,                  // [2][8192] tagged words
    float* __restrict__ Hf32,
    float* __restrict__ Cbuf,
    const float* __restrict__ mask,
    const float* __restrict__ dm,
    float* __restrict__ Y,
    float* __restrict__ out,
    int l, int c,
    const int* __restrict__ trainPtr,
    // fused-proj args (chunk c+1)
    const float* __restrict__ xin, int do_proj,
    const float* __restrict__ Wih, const float* __restrict__ Wgi,
    const float* __restrict__ Wli,
    const float* __restrict__ bih, const float* __restrict__ bhh,
    const float* __restrict__ bgi, const float* __restrict__ bgs,
    unsigned short* __restrict__ PtW)
{
    __shared__ uint4 h16[16 * 4 * 32];       // 32 KB
    __shared__ float Dst[BAT * DSTR];        // 10.4 KB
    __shared__ float hout[BAT * HOSTR];      //  2.5 KB
    __shared__ unsigned short As[128 * PASTR]; // 18.4 KB (proj path)
    __shared__ unsigned short Bs[64 * PASTR];  //  9.2 KB (proj path)

    const int tid = threadIdx.x;
    const int rev = (l == 1);

    if (blockIdx.x >= NB) {
        if (do_proj) {
            int j0 = ((int)blockIdx.x - NB) * 2;
            proj_tile(j0, xin, (c + 1) * CH, rev, Wih, Wgi, Wli,
                      bih, bhh, bgi, bgs, PtW, As, Bs, tid);
            proj_tile(j0 + 1, xin, (c + 1) * CH, rev, Wih, Wgi, Wli,
                      bih, bhh, bgi, bgs, PtW, As, Bs, tid);
        }
        return;
    }

    const int u0 = blockIdx.x * UPB;
    const int b = tid & 31;
    const int ul = tid >> 5;
    const int lane = tid & 63;
    const int wv = tid >> 6;
    const int row15 = lane & 15;
    const int koff = (lane >> 4) * 8;

    // wave -> MFMA tile map (verified r5-r10)
    const int mtA = wv / 5, ntA = wv % 5;
    const int has2 = (wv < 2);
    const int mtB = 1, ntB = 3 + wv;

    // weight B-fragments in registers (once per chunk)
    bfrag wA[16], wB[16];
    {
        const float* rA = (ntA < 4) ? (Whh + ((size_t)(ntA * 512 + u0 + row15)) * 512)
                                    : (Wgs + (size_t)(u0 + row15) * 512);
#pragma unroll
        for (int ks = 0; ks < 16; ks++) {
            int k = koff + ks * 32;
            float4 x0 = *(const float4*)(rA + k);
            float4 x1 = *(const float4*)(rA + k + 4);
            bfrag f;
            f[0] = (short)f2bf(x0.x); f[1] = (short)f2bf(x0.y);
            f[2] = (short)f2bf(x0.z); f[3] = (short)f2bf(x0.w);
            f[4] = (short)f2bf(x1.x); f[5] = (short)f2bf(x1.y);
            f[6] = (short)f2bf(x1.z); f[7] = (short)f2bf(x1.w);
            wA[ks] = f;
        }
        if (has2) {
            const float* rB = (ntB < 4) ? (Whh + ((size_t)(ntB * 512 + u0 + row15)) * 512)
                                        : (Wgs + (size_t)(u0 + row15) * 512);
#pragma unroll
            for (int ks = 0; ks < 16; ks++) {
                int k = koff + ks * 32;
                float4 x0 = *(const float4*)(rB + k);
                float4 x1 = *(const float4*)(rB + k + 4);
                bfrag f;
                f[0] = (short)f2bf(x0.x); f[1] = (short)f2bf(x0.y);
                f[2] = (short)f2bf(x0.z); f[3] = (short)f2bf(x0.w);
                f[4] = (short)f2bf(x1.x); f[5] = (short)f2bf(x1.y);
                f[6] = (short)f2bf(x1.z); f[7] = (short)f2bf(x1.w);
                wB[ks] = f;
            }
        } else {
#pragma unroll
            for (int ks = 0; ks < 16; ks++) wB[ks] = wA[ks];
        }
    }

    const int u = u0 + ul;
    float h = Hf32[b * HID + u];
    float cc = Cbuf[b * HID + u];
    const int train = *trainPtr;
    const float dmv = train ? dm[b * HID + u] : 1.0f;

    const char* hb = (const char*)h16;
    const char* haA = hb + (size_t)(lane >> 4) * 512 + (mtA * 16 + row15) * 16;
    const char* haB = hb + (size_t)(lane >> 4) * 512 + (mtB * 16 + row15) * 16;

    for (int s = 0; s < CH; s++) {
        const int t = c * CH + s;
        const int par = t & 1;
        const int tPhys = rev ? (SEQ - 1 - t) : t;

        // --- gather h_t: batch-issued loads; SELECTIVE retry on stale words
        const u64* srcb = Htag + (size_t)par * 8192 + (size_t)ul * 512 + b;
        u64 v[16];
        {
            GATHER16
            VMWAIT
            const unsigned ex = (unsigned)t;
            unsigned bad = 0;
#pragma unroll
            for (int j = 0; j < 16; j++) bad |= ((unsigned)(v[j] >> 32)) ^ ex;
            while (bad) {
                __builtin_amdgcn_s_sleep(1);
#pragma unroll
                for (int j = 0; j < 16; j++)
                    if (((unsigned)(v[j] >> 32)) != ex)
                        v[j] = __hip_atomic_load(srcb + (size_t)j * 32,
                                                 __ATOMIC_RELAXED, __HIP_MEMORY_SCOPE_AGENT);
                bad = 0;
#pragma unroll
                for (int j = 0; j < 16; j++) bad |= ((unsigned)(v[j] >> 32)) ^ ex;
            }
#pragma unroll
            for (int q = 0; q < 4; q++) {
                uint4 wq;
                wq.x = (unsigned)v[4 * q + 0];
                wq.y = (unsigned)v[4 * q + 1];
                wq.z = (unsigned)v[4 * q + 2];
                wq.w = (unsigned)v[4 * q + 3];
                h16[(ul * 4 + q) * 32 + b] = wq;
            }
        }

        // --- P / mask loads (bf16, coalesced; hidden under stage+MFMA)
        const unsigned short* Pb = PtR + (size_t)s * NG * BAT;
        float pi = bf2f(Pb[(size_t)(0 * HID + u) * BAT + b]);
        float pf = bf2f(Pb[(size_t)(1 * HID + u) * BAT + b]);
        float pg = bf2f(Pb[(size_t)(2 * HID + u) * BAT + b]);
        float po = bf2f(Pb[(size_t)(3 * HID + u) * BAT + b]);
        float pr = bf2f(Pb[(size_t)(4 * HID + u) * BAT + b]);
        float xl = bf2f(Pb[(size_t)(5 * HID + u) * BAT + b]);
        float mk = mask[(size_t)tPhys * BAT + b];
        __syncthreads();

        // --- MFMA, 2-way split accumulator chains
        {
            f32x4 aA0 = {0.f,0.f,0.f,0.f}, aA1 = {0.f,0.f,0.f,0.f};
            f32x4 aB0 = {0.f,0.f,0.f,0.f}, aB1 = {0.f,0.f,0.f,0.f};
#pragma unroll
            for (int ks = 0; ks < 8; ks++) {
                aA0 = __builtin_amdgcn_mfma_f32_16x16x32_bf16(
                        *(const bfrag*)(haA + (size_t)ks * 2048), wA[ks], aA0, 0, 0, 0);
                aA1 = __builtin_amdgcn_mfma_f32_16x16x32_bf16(
                        *(const bfrag*)(haA + (size_t)(ks + 8) * 2048), wA[ks + 8], aA1, 0, 0, 0);
                if (has2) {
                    aB0 = __builtin_amdgcn_mfma_f32_16x16x32_bf16(
                            *(const bfrag*)(haB + (size_t)ks * 2048), wB[ks], aB0, 0, 0, 0);
                    aB1 = __builtin_amdgcn_mfma_f32_16x16x32_bf16(
                            *(const bfrag*)(haB + (size_t)(ks + 8) * 2048), wB[ks + 8], aB1, 0, 0, 0);
                }
            }
            f32x4 acA = aA0 + aA1;
            int mrA = mtA * 16 + (lane >> 4) * 4, clA = ntA * 16 + row15;
#pragma unroll
            for (int r = 0; r < 4; r++) Dst[(mrA + r) * DSTR + clA] = acA[r];
            if (has2) {
                f32x4 acB = aB0 + aB1;
                int mrB = mtB * 16 + (lane >> 4) * 4, clB = ntB * 16 + row15;
#pragma unroll
                for (int r = 0; r < 4; r++) Dst[(mrB + r) * DSTR + clB] = acB[r];
            }
        }
        __syncthreads();

        // --- pointwise: hn first, publish ASAP, then c-update and outputs
        float gi = sigf(pi + Dst[b * DSTR + 0  + ul]);
        float gf = sigf(pf + Dst[b * DSTR + 16 + ul]);
        float gg = tanhf(pg + Dst[b * DSTR + 32 + ul]);
        float go = sigf(po + Dst[b * DSTR + 48 + ul]);
        float gr = sigf(pr + Dst[b * DSTR + 64 + ul]);
        float ct = gf * cc + gi * gg;
        float hr_ = go * tanhf(ct);
        float h2 = (gr * hr_ + (1.f - gr) * xl) * dmv;
        float hn = mk * h2 + (1.f - mk) * h;

        {
            unsigned mybf = (unsigned)f2bf(hn);
            unsigned part = __shfl_xor(mybf, 32, 64);
            if (lane < 32) {
                u64 pv = (u64)(mybf | (part << 16)) | ((u64)(unsigned)(t + 1) << 32);
                u64* dst = Htag + (size_t)(par ^ 1) * 8192
                                + ((size_t)(blockIdx.x * 8 + wv)) * 32 + b;
                asm volatile("global_store_dwordx2 %0, %1, off sc0 sc1"
                             :: "v"(dst), "v"(pv) : "memory");
            }
        }
        cc = mk * ct + (1.f - mk) * cc;
        h = hn;

        // coalesced output via padded LDS transpose
        hout[b * HOSTR + ul] = hn;
        __syncthreads();
        if (tid < 128) {
            int bb = tid >> 2, q = tid & 3;
            float4 o = *(const float4*)&hout[bb * HOSTR + 4 * q];
            if (l == 0)
                *(float4*)&Y[(size_t)t * BAT * HID + bb * HID + u0 + 4 * q] = o;
            else
                *(float4*)&out[(size_t)bb * SEQ * HID
                               + (size_t)(SEQ - 1 - t) * HID + u0 + 4 * q] = o;
        }
    }

    Hf32[b * HID + u] = h;
    Cbuf[b * HID + u] = cc;
}

// ---------------------------------------------------------------------------
extern "C" void kernel_launch(void* const* d_in, const int* in_sizes, int n_in,
                              void* d_out, int out_size, void* d_ws, size_t ws_size,
                              hipStream_t stream) {
    const float* x        = (const float*)d_in[0];
    const float* mask     = (const float*)d_in[1];
    const float* W_ih     = (const float*)d_in[2];
    const float* b_ih     = (const float*)d_in[3];
    const float* W_hh     = (const float*)d_in[4];
    const float* b_hh     = (const float*)d_in[5];
    const float* Wg_in    = (const float*)d_in[6];
    const float* bg_in    = (const float*)d_in[7];
    const float* Wg_state = (const float*)d_in[8];
    const float* bg_state = (const float*)d_in[9];
    const float* Wl_in    = (const float*)d_in[10];
    const float* drop     = (const float*)d_in[11];
    const int*   train    = (const int*)d_in[12];
    float* out = (float*)d_out;

    // ws layout:
    //   Pt0,Pt1 : CH*3072*32 bf16 each = 6.29 MB x2
    //   Y       : 512*32*512 fp32      = 33.55 MB
    //   Htag    : 2*8192 u64           = 128 KB
    //   Hf32,Cbuf : 64 KB each          (total ~46.4 MB)
    unsigned short* Pt0 = (unsigned short*)d_ws;
    unsigned short* Pt1 = Pt0 + (size_t)CH * NG * BAT;
    float* Y    = (float*)(Pt1 + (size_t)CH * NG * BAT);
    u64*   Htag = (u64*)(Y + (size_t)SEQ * BAT * HID);
    float* Hf32 = (float*)(Htag + 2 * 8192);
    float* Cbuf = Hf32 + BAT * HID;

    for (int l = 0; l < 2; l++) {
        const int rev = l;
        const float* Wih = W_ih + (size_t)l * 4 * HID * HID;
        const float* Whh = W_hh + (size_t)l * 4 * HID * HID;
        const float* Wgi = Wg_in + (size_t)l * HID * HID;
        const float* Wli = Wl_in + (size_t)l * HID * HID;
        const float* bih = b_ih + (size_t)l * 4 * HID;
        const float* bhh = b_hh + (size_t)l * 4 * HID;
        const float* bgi = bg_in + (size_t)l * HID;
        const float* dm  = drop + (size_t)l * BAT * HID;
        const float* xin = l ? Y : x;

        hipMemsetAsync(Htag, 0,
                       (size_t)2 * 8192 * 8 + (size_t)2 * BAT * HID * 4,
                       stream);

        // chunk 0 projection (standalone)
        proj_gemm<<<384, 512, 0, stream>>>(
            xin, 0, rev, Wih, Wgi, Wli, bih, bhh, bgi, bg_state, Pt0);

        for (int c = 0; c < SEQ / CH; c++) {
            unsigned short* PtR = (c & 1) ? Pt1 : Pt0;
            unsigned short* PtW = (c & 1) ? Pt0 : Pt1;
            scan_chunk<<<NB + NPROJB, 512, 0, stream>>>(
                PtR, Whh, Wg_state, Htag, Hf32, Cbuf, mask, dm, Y, out,
                l, c, train,
                xin, (c < SEQ / CH - 1) ? 1 : 0,
                Wih, Wgi, Wli, bih, bhh, bgi, bg_state, PtW);
        }
    }
}